// Round 2
// baseline (766.970 us; speedup 1.0000x reference)
//
#include <hip/hip_runtime.h>
#include <hip/hip_bf16.h>

// ---------------- types ----------------
typedef unsigned short u16;
typedef u16   u16x4 __attribute__((ext_vector_type(4)));
typedef u16   u16x8 __attribute__((ext_vector_type(8)));
typedef short s16x8 __attribute__((ext_vector_type(8)));
typedef float f32x4 __attribute__((ext_vector_type(4)));

// Problem constants
#define NB   64
#define NL   512
#define ND   512
#define NA   8
#define K2   1024        // 2*D
#define MROWS 32768      // B*L

__device__ __forceinline__ float b2f(u16 u) {
    unsigned int x = ((unsigned int)u) << 16;
    return __uint_as_float(x);
}
__device__ __forceinline__ u16 f2b(float f) {
    unsigned int x = __float_as_uint(f);
    unsigned int r = (x + 0x7fffu + ((x >> 16) & 1u)) >> 16;
    return (u16)r;
}

// permuted column position for original k within a 64-col K-block:
// stored order puts each lane's 8 MFMA elements contiguous:
// c = (kk*4+g)*8 + (e&3) + 4*(e>>2)  where k = kk*32 + 4g + (e&3) + 16*(e>>2)
__device__ __forceinline__ int permc(int k) {
    int ks  = k >> 6;
    int kr  = k & 63;
    int kk  = kr >> 5;
    int k32 = kr & 31;
    int h   = k32 >> 4;
    int rem = k32 & 15;
    int g   = rem >> 2;
    int e0  = rem & 3;
    return ks * 64 + kk * 32 + g * 8 + h * 4 + e0;
}

__device__ __forceinline__ void gload16(const u16* g, u16* l) {
    __builtin_amdgcn_global_load_lds(
        (const __attribute__((address_space(1))) unsigned int*)g,
        (__attribute__((address_space(3))) unsigned int*)l, 16, 0, 0);
}

// ---------------- kernel 1: build permuted bf16 Batch [32768][1024] ----------------
__global__ void build_batch(const float* __restrict__ H, const float* __restrict__ U,
                            u16* __restrict__ Bt) {
    size_t stride = (size_t)gridDim.x * blockDim.x;
    for (size_t idx = (size_t)blockIdx.x * blockDim.x + threadIdx.x;
         idx < (size_t)MROWS * 256; idx += stride) {
        int r  = (int)(idx >> 8);
        int c  = ((int)idx & 255) << 2;       // permuted col (multiple of 4)
        int ks = c >> 6;
        int w64 = c & 63;
        int cq = w64 >> 3;
        int h  = (w64 >> 2) & 1;
        int kbase = ks * 64 + (cq >> 2) * 32 + (cq & 3) * 4 + h * 16;
        const float* src;
        if (kbase < ND) src = H + (size_t)r * ND + kbase;
        else { int b = r >> 9; src = U + (size_t)b * ND + (kbase - ND); }
        f32x4 v = *(const f32x4*)src;
        u16x4 o;
        o[0] = f2b(v[0]); o[1] = f2b(v[1]); o[2] = f2b(v[2]); o[3] = f2b(v[3]);
        *(u16x4*)(Bt + (size_t)r * K2 + c) = o;
    }
}

// ---------------- kernel 2: W (A,1024,512) f32 -> Wt (A,512,1024) bf16 permuted ----------------
__global__ void build_wt(const float* __restrict__ Wmf, const float* __restrict__ Wpf,
                         u16* __restrict__ Wm, u16* __restrict__ Wp) {
    __shared__ float ld[32][65];
    int bid = blockIdx.x;
    int kt  = bid & 31;
    int dt  = (bid >> 5) & 7;
    int a   = (bid >> 8) & 7;
    int mat = bid >> 11;
    const float* W = mat ? Wpf : Wmf;
    u16* Wt = mat ? Wp : Wm;
    int k0 = kt * 32, d0 = dt * 64;
    int t = threadIdx.x;
    #pragma unroll
    for (int it = 0; it < 8; ++it) {
        int lin = it * 256 + t;
        int i = lin >> 6, j = lin & 63;
        ld[i][j] = W[((size_t)a * K2 + k0 + i) * ND + d0 + j];
    }
    __syncthreads();
    #pragma unroll
    for (int it = 0; it < 8; ++it) {
        int lin = it * 256 + t;
        int dl = lin >> 5, kl = lin & 31;
        int k = k0 + kl;
        Wt[((size_t)a * ND + d0 + dl) * K2 + permc(k)] = f2b(ld[kl][dl]);
    }
}

// ---------------- kernel 3: 8-phase dual GEMM + gate + item write ----------------
// BM=256, BN=128, BK=64, 8 waves (2M x 4N), double-buffered LDS, counted vmcnt.
#define BAR()    asm volatile("s_barrier" ::: "memory")
#define WAITV(n) asm volatile("s_waitcnt vmcnt(" #n ")" ::: "memory")
#define LGKM0()  do { asm volatile("s_waitcnt lgkmcnt(0)" ::: "memory"); \
                      __builtin_amdgcn_sched_barrier(0); } while (0)

#define RD_AQ(Q) \
    _Pragma("unroll") for (int f_ = 0; f_ < 4; ++f_) \
    _Pragma("unroll") for (int kk_ = 0; kk_ < 2; ++kk_) \
        af[f_ * 2 + kk_] = rdA(cur, (Q), f_, kk_);

#define RD_FM() \
    _Pragma("unroll") for (int j_ = 0; j_ < 2; ++j_) \
    _Pragma("unroll") for (int kk_ = 0; kk_ < 2; ++kk_) \
        fm[j_ * 2 + kk_] = rdB(cur, 0, j_, kk_);

#define RD_FP() \
    _Pragma("unroll") for (int j_ = 0; j_ < 2; ++j_) \
    _Pragma("unroll") for (int kk_ = 0; kk_ < 2; ++kk_) \
        fp[j_ * 2 + kk_] = rdB(cur, 1, j_, kk_);

#define MMA_M(F0) do { \
    _Pragma("unroll") for (int kk_ = 0; kk_ < 2; ++kk_) \
    _Pragma("unroll") for (int f_ = 0; f_ < 4; ++f_) \
    _Pragma("unroll") for (int j_ = 0; j_ < 2; ++j_) \
        accM[(F0) + f_][j_] = __builtin_amdgcn_mfma_f32_16x16x32_bf16( \
            af[f_ * 2 + kk_], fm[j_ * 2 + kk_], accM[(F0) + f_][j_], 0, 0, 0); \
} while (0)

#define MMA_P(F0) do { \
    _Pragma("unroll") for (int kk_ = 0; kk_ < 2; ++kk_) \
    _Pragma("unroll") for (int f_ = 0; f_ < 4; ++f_) \
    _Pragma("unroll") for (int j_ = 0; j_ < 2; ++j_) \
        accP[(F0) + f_][j_] = __builtin_amdgcn_mfma_f32_16x16x32_bf16( \
            af[f_ * 2 + kk_], fp[j_ * 2 + kk_], accP[(F0) + f_][j_], 0, 0, 0); \
} while (0)

__global__ __launch_bounds__(512, 2) void gemm8_k(
    const u16* __restrict__ Bt, const u16* __restrict__ Wm, const u16* __restrict__ Wp,
    const float* __restrict__ bm, const float* __restrict__ bp,
    u16* __restrict__ item, int a0, int log2na, int nwg) {
    __shared__ u16 As[2][256 * 64];     // 64 KB
    __shared__ u16 Bms[2][128 * 64];    // 32 KB
    __shared__ u16 Bps[2][128 * 64];    // 32 KB

    int bid = blockIdx.x;
    int chunk = nwg >> 3;                       // XCD-aware swizzle (nwg % 8 == 0)
    int b = (bid & 7) * chunk + (bid >> 3);
    int nt = b & 3;                             // N-tile fastest: share A panel
    int al = (b >> 2) & ((1 << log2na) - 1);    // then aspect: same A panel
    int mt = b >> (2 + log2na);
    int a  = a0 + al;

    int tid = threadIdx.x;
    int lane = tid & 63;
    int w  = tid >> 6;        // 0..7
    int wr = w >> 2;          // 0..1  (M half)
    int wc = w & 3;           // 0..3  (N quarter)
    int g = lane >> 4, r15 = lane & 15;

    const u16* Abase = Bt + (size_t)(mt * 256) * K2;
    const u16* Mbase = Wm + ((size_t)a * ND + nt * 128) * K2;
    const u16* Pbase = Wp + ((size_t)a * ND + nt * 128) * K2;

    // staging: linear LDS dest (base + tid*16B), inverse-swizzled global source
    auto stageA = [&](int buf, int ks, int r) {
        int row = r * 64 + (tid >> 3);
        int sl = tid & 7;
        int q = sl ^ (row & 7);
        gload16(Abase + (size_t)row * K2 + ks * 64 + q * 8, &As[buf][row * 64 + sl * 8]);
    };
    auto stageBm = [&](int buf, int ks, int r) {
        int row = r * 64 + (tid >> 3);
        int sl = tid & 7;
        int q = sl ^ (row & 7);
        gload16(Mbase + (size_t)row * K2 + ks * 64 + q * 8, &Bms[buf][row * 64 + sl * 8]);
    };
    auto stageBp = [&](int buf, int ks, int r) {
        int row = r * 64 + (tid >> 3);
        int sl = tid & 7;
        int q = sl ^ (row & 7);
        gload16(Pbase + (size_t)row * K2 + ks * 64 + q * 8, &Bps[buf][row * 64 + sl * 8]);
    };
    // swizzled fragment reads
    auto rdA = [&](int buf, int qd, int f, int kk) -> s16x8 {
        int row = wr * 128 + qd * 64 + f * 16 + r15;
        int slot = (kk * 4 + g) ^ (row & 7);
        return *(const s16x8*)&As[buf][row * 64 + slot * 8];
    };
    auto rdB = [&](int buf, int mat, int j, int kk) -> s16x8 {
        int row = wc * 32 + j * 16 + r15;
        int slot = (kk * 4 + g) ^ (row & 7);
        return mat ? *(const s16x8*)&Bps[buf][row * 64 + slot * 8]
                   : *(const s16x8*)&Bms[buf][row * 64 + slot * 8];
    };

    f32x4 accM[8][2], accP[8][2];
    #pragma unroll
    for (int i = 0; i < 8; ++i)
        #pragma unroll
        for (int j = 0; j < 2; ++j) { accM[i][j] = 0.0f; accP[i][j] = 0.0f; }

    s16x8 af[8], fm[4], fp[4];

    // ---- prologue: stage buf0 in read-order; keep newest 4 in flight ----
    stageA(0, 0, 0); stageA(0, 0, 2);      // A rows Q0,Q2  (P1 needs)
    stageBm(0, 0, 0); stageBm(0, 0, 1);    // Bm            (P1 needs)
    stageBp(0, 0, 0); stageBp(0, 0, 1);    // Bp            (P2 needs)
    stageA(0, 0, 1); stageA(0, 0, 3);      // A rows Q1,Q3  (P3 needs)
    WAITV(4); BAR();

    // ---- steady loop: K-steps 0..14, staging t+1 ----
    for (int t = 0; t < 15; ++t) {
        int cur = t & 1, nxt = cur ^ 1, kn = t + 1;
        // P1: A q0 + Bm reads; stage A.Q0Q2(t+1); MFMA M-low
        RD_AQ(0) RD_FM()
        stageA(nxt, kn, 0); stageA(nxt, kn, 2);
        BAR(); LGKM0();
        __builtin_amdgcn_s_setprio(1); MMA_M(0); __builtin_amdgcn_s_setprio(0);
        WAITV(4); BAR();
        // P2: Bp reads; stage Bm(t+1); MFMA P-low
        RD_FP()
        stageBm(nxt, kn, 0); stageBm(nxt, kn, 1);
        BAR(); LGKM0();
        __builtin_amdgcn_s_setprio(1); MMA_P(0); __builtin_amdgcn_s_setprio(0);
        WAITV(4); BAR();
        // P3: A q1 reads; stage Bp(t+1); MFMA M-high
        RD_AQ(1)
        stageBp(nxt, kn, 0); stageBp(nxt, kn, 1);
        BAR(); LGKM0();
        __builtin_amdgcn_s_setprio(1); MMA_M(4); __builtin_amdgcn_s_setprio(0);
        BAR();
        // P4: no reads; stage A.Q1Q3(t+1); MFMA P-high
        stageA(nxt, kn, 1); stageA(nxt, kn, 3);
        BAR();
        __builtin_amdgcn_s_setprio(1); MMA_P(4); __builtin_amdgcn_s_setprio(0);
        WAITV(4); BAR();
    }

    // ---- epilogue K-step 15 (cur = 1): drain 4 -> 2 -> 0 ----
    {
        const int cur = 1;
        RD_AQ(0) RD_FM()
        BAR(); LGKM0();
        __builtin_amdgcn_s_setprio(1); MMA_M(0); __builtin_amdgcn_s_setprio(0);
        WAITV(2); BAR();
        RD_FP()
        BAR(); LGKM0();
        __builtin_amdgcn_s_setprio(1); MMA_P(0); __builtin_amdgcn_s_setprio(0);
        WAITV(0); BAR();
        RD_AQ(1)
        BAR(); LGKM0();
        __builtin_amdgcn_s_setprio(1); MMA_M(4); __builtin_amdgcn_s_setprio(0);
        BAR();
        __builtin_amdgcn_s_setprio(1); MMA_P(4); __builtin_amdgcn_s_setprio(0);
    }

    // ---- C epilogue: bias + sigmoid gate, write item bf16 ----
    #pragma unroll
    for (int j = 0; j < 2; ++j) {
        int gcol = nt * 128 + wc * 32 + j * 16 + r15;
        float bmv = bm[a * ND + gcol];
        float bpv = bp[a * ND + gcol];
        #pragma unroll
        for (int i = 0; i < 8; ++i) {
            int rowb = mt * 256 + wr * 128 + i * 16 + g * 4;
            #pragma unroll
            for (int jj = 0; jj < 4; ++jj) {
                float m = accM[i][j][jj] + bmv;
                float p = accP[i][j][jj] + bpv;
                float gate = 1.0f / (1.0f + __expf(-m));
                item[((size_t)al * MROWS + rowb + jj) * ND + gcol] = f2b(gate * p);
            }
        }
    }
}

// ---------------- kernel 4: scores + softmax(L) + weighted sum ----------------
// one block per (b', a'); item rows R' = bl*4096 + 8*l' + a'
__global__ __launch_bounds__(512) void attn_out_k(
    const u16* __restrict__ item, const float* __restrict__ asp,
    float* __restrict__ out, int b0) {
    __shared__ float asp_s[512];
    __shared__ float attn[512];
    __shared__ float red[4][512];
    int t = threadIdx.x;
    int bl = blockIdx.x >> 3;
    int ap = blockIdx.x & 7;
    int bg = b0 + bl;

    asp_s[t] = asp[ap * ND + t];
    __syncthreads();

    // scores: each thread does one l' row (dot over D)
    const u16* rp = item + ((size_t)bl * 4096 + (size_t)t * 8 + ap) * ND;
    float s = 0.0f;
    for (int j = 0; j < 64; ++j) {
        u16x8 v = *(const u16x8*)(rp + j * 8);
        #pragma unroll
        for (int e = 0; e < 8; ++e) s += b2f(v[e]) * asp_s[j * 8 + e];
    }
    red[0][t] = s;
    __syncthreads();
    for (int off = 256; off > 0; off >>= 1) {
        if (t < off) red[0][t] = fmaxf(red[0][t], red[0][t + off]);
        __syncthreads();
    }
    float mx = red[0][0];
    __syncthreads();
    float p = __expf(s - mx);
    red[0][t] = p;
    __syncthreads();
    for (int off = 256; off > 0; off >>= 1) {
        if (t < off) red[0][t] += red[0][t + off];
        __syncthreads();
    }
    float inv = 1.0f / red[0][0];
    attn[t] = p * inv;
    __syncthreads();

    // weighted sum: 4 l'-groups x 128 d-threads (4 d each)
    int gq = t >> 7, u = t & 127;
    float a0v = 0.f, a1v = 0.f, a2v = 0.f, a3v = 0.f;
    const u16* base2 = item + ((size_t)bl * 4096 + ap) * ND + 4 * u;
    for (int l = gq; l < 512; l += 4) {
        float wv = attn[l];
        u16x4 v = *(const u16x4*)(base2 + (size_t)l * 8 * ND);
        a0v += wv * b2f(v[0]); a1v += wv * b2f(v[1]);
        a2v += wv * b2f(v[2]); a3v += wv * b2f(v[3]);
    }
    red[gq][4 * u + 0] = a0v; red[gq][4 * u + 1] = a1v;
    red[gq][4 * u + 2] = a2v; red[gq][4 * u + 3] = a3v;
    __syncthreads();
    float o = red[0][t] + red[1][t] + red[2][t] + red[3][t];
    out[((size_t)bg * NA + ap) * ND + t] = o;
}

// ---------------- launcher ----------------
extern "C" void kernel_launch(void* const* d_in, const int* in_sizes, int n_in,
                              void* d_out, int out_size, void* d_ws, size_t ws_size,
                              hipStream_t stream) {
    const float* H   = (const float*)d_in[0];
    const float* U   = (const float*)d_in[1];
    const float* asp = (const float*)d_in[2];
    const float* Wmf = (const float*)d_in[3];
    const float* bmf = (const float*)d_in[4];
    const float* Wpf = (const float*)d_in[5];
    const float* bpf = (const float*)d_in[6];
    float* out = (float*)d_out;

    char* ws = (char*)d_ws;
    const size_t BATCH_BYTES = (size_t)MROWS * K2 * 2;        // 64 MB
    const size_t WT_BYTES    = (size_t)NA * ND * K2 * 2;      // 8 MB each
    u16* Bt   = (u16*)(ws);
    u16* Wm   = (u16*)(ws + BATCH_BYTES);
    u16* Wp   = (u16*)(ws + BATCH_BYTES + WT_BYTES);
    u16* item = (u16*)(ws + BATCH_BYTES + 2 * WT_BYTES);
    size_t fixed = BATCH_BYTES + 2 * WT_BYTES;                 // 80 MB
    const size_t ITEM_PER_ASPECT = (size_t)MROWS * ND * 2;     // 32 MB
    size_t avail = (ws_size > fixed) ? (ws_size - fixed) : 0;
    int na = (int)(avail / ITEM_PER_ASPECT);
    if (na > NA) na = NA;
    if (na < 1) na = 1;
    int log2na = 0;                                            // round down to pow2
    while ((2 << log2na) <= na) ++log2na;
    na = 1 << log2na;

    build_batch<<<4096, 256, 0, stream>>>(H, U, Bt);
    build_wt<<<4096, 256, 0, stream>>>(Wmf, Wpf, Wm, Wp);

    for (int a0 = 0; a0 < NA; a0 += na) {
        int n = (na < NA - a0) ? na : (NA - a0);
        gemm8_k<<<n * 512, 512, 0, stream>>>(Bt, Wm, Wp, bmf, bpf, item, a0, log2na, n * 512);
        attn_out_k<<<n * 64, 512, 0, stream>>>(item, asp, out, a0 * 8);
    }
}

// Round 3
// 700.201 us; speedup vs baseline: 1.0954x; 1.0954x over previous
//
#include <hip/hip_runtime.h>
#include <hip/hip_bf16.h>

// ---------------- types ----------------
typedef unsigned short u16;
typedef u16   u16x4 __attribute__((ext_vector_type(4)));
typedef u16   u16x8 __attribute__((ext_vector_type(8)));
typedef short s16x8 __attribute__((ext_vector_type(8)));
typedef float f32x4 __attribute__((ext_vector_type(4)));

// Problem constants
#define NB   64
#define NL   512
#define ND   512
#define NA   8
#define K2   1024        // 2*D
#define MROWS 32768      // B*L

__device__ __forceinline__ float b2f(u16 u) {
    unsigned int x = ((unsigned int)u) << 16;
    return __uint_as_float(x);
}
__device__ __forceinline__ u16 f2b(float f) {
    unsigned int x = __float_as_uint(f);
    unsigned int r = (x + 0x7fffu + ((x >> 16) & 1u)) >> 16;
    return (u16)r;
}

// permuted column position for original k within a 64-col K-block
__device__ __forceinline__ int permc(int k) {
    int ks  = k >> 6;
    int kr  = k & 63;
    int kk  = kr >> 5;
    int k32 = kr & 31;
    int h   = k32 >> 4;
    int rem = k32 & 15;
    int g   = rem >> 2;
    int e0  = rem & 3;
    return ks * 64 + kk * 32 + g * 8 + h * 4 + e0;
}

__device__ __forceinline__ void gload16(const u16* g, u16* l) {
    __builtin_amdgcn_global_load_lds(
        (const __attribute__((address_space(1))) unsigned int*)g,
        (__attribute__((address_space(3))) unsigned int*)l, 16, 0, 0);
}

// ---------------- kernel 1: build permuted bf16 Batch [32768][1024] ----------------
__global__ void build_batch(const float* __restrict__ H, const float* __restrict__ U,
                            u16* __restrict__ Bt) {
    size_t stride = (size_t)gridDim.x * blockDim.x;
    for (size_t idx = (size_t)blockIdx.x * blockDim.x + threadIdx.x;
         idx < (size_t)MROWS * 256; idx += stride) {
        int r  = (int)(idx >> 8);
        int c  = ((int)idx & 255) << 2;       // permuted col (multiple of 4)
        int ks = c >> 6;
        int w64 = c & 63;
        int cq = w64 >> 3;
        int h  = (w64 >> 2) & 1;
        int kbase = ks * 64 + (cq >> 2) * 32 + (cq & 3) * 4 + h * 16;
        const float* src;
        if (kbase < ND) src = H + (size_t)r * ND + kbase;
        else { int b = r >> 9; src = U + (size_t)b * ND + (kbase - ND); }
        f32x4 v = *(const f32x4*)src;
        u16x4 o;
        o[0] = f2b(v[0]); o[1] = f2b(v[1]); o[2] = f2b(v[2]); o[3] = f2b(v[3]);
        *(u16x4*)(Bt + (size_t)r * K2 + c) = o;
    }
}

// ---------------- kernel 2: W (A,1024,512) f32 -> Wt (A,512,1024) bf16 permuted ----------------
__global__ void build_wt(const float* __restrict__ Wmf, const float* __restrict__ Wpf,
                         u16* __restrict__ Wm, u16* __restrict__ Wp) {
    __shared__ float ld[32][65];
    int bid = blockIdx.x;
    int kt  = bid & 31;
    int dt  = (bid >> 5) & 7;
    int a   = (bid >> 8) & 7;
    int mat = bid >> 11;
    const float* W = mat ? Wpf : Wmf;
    u16* Wt = mat ? Wp : Wm;
    int k0 = kt * 32, d0 = dt * 64;
    int t = threadIdx.x;
    #pragma unroll
    for (int it = 0; it < 8; ++it) {
        int lin = it * 256 + t;
        int i = lin >> 6, j = lin & 63;
        ld[i][j] = W[((size_t)a * K2 + k0 + i) * ND + d0 + j];
    }
    __syncthreads();
    #pragma unroll
    for (int it = 0; it < 8; ++it) {
        int lin = it * 256 + t;
        int dl = lin >> 5, kl = lin & 31;
        int k = k0 + kl;
        Wt[((size_t)a * ND + d0 + dl) * K2 + permc(k)] = f2b(ld[kl][dl]);
    }
}

// ---------------- kernel 3: deep-pipelined dual GEMM + gate + fused scores ----------------
// BM=256, BN=128, BK=64, 8 waves (2M x 4N), double-buffered LDS.
// Staging for K-step t+2 spread over K-step t; single vmcnt(6) per K-step.
#define BAR()    asm volatile("s_barrier" ::: "memory")
#define WAITV(n) asm volatile("s_waitcnt vmcnt(" #n ")" ::: "memory")
#define LGKM0()  do { asm volatile("s_waitcnt lgkmcnt(0)" ::: "memory"); \
                      __builtin_amdgcn_sched_barrier(0); } while (0)
#define PRIO1    __builtin_amdgcn_s_setprio(1);
#define PRIO0    __builtin_amdgcn_s_setprio(0);

#define RD_AQ(C,Q) \
    _Pragma("unroll") for (int f_ = 0; f_ < 4; ++f_) \
    _Pragma("unroll") for (int kk_ = 0; kk_ < 2; ++kk_) \
        af[f_ * 2 + kk_] = rdA((C), (Q), f_, kk_);

#define RD_FM(C) \
    _Pragma("unroll") for (int j_ = 0; j_ < 2; ++j_) \
    _Pragma("unroll") for (int kk_ = 0; kk_ < 2; ++kk_) \
        fm[j_ * 2 + kk_] = rdB((C), 0, j_, kk_);

#define RD_FP(C) \
    _Pragma("unroll") for (int j_ = 0; j_ < 2; ++j_) \
    _Pragma("unroll") for (int kk_ = 0; kk_ < 2; ++kk_) \
        fp[j_ * 2 + kk_] = rdB((C), 1, j_, kk_);

#define MMA_M(F0) \
    _Pragma("unroll") for (int kk_ = 0; kk_ < 2; ++kk_) \
    _Pragma("unroll") for (int f_ = 0; f_ < 4; ++f_) \
    _Pragma("unroll") for (int j_ = 0; j_ < 2; ++j_) \
        accM[(F0) + f_][j_] = __builtin_amdgcn_mfma_f32_16x16x32_bf16( \
            af[f_ * 2 + kk_], fm[j_ * 2 + kk_], accM[(F0) + f_][j_], 0, 0, 0);

#define MMA_P(F0) \
    _Pragma("unroll") for (int kk_ = 0; kk_ < 2; ++kk_) \
    _Pragma("unroll") for (int f_ = 0; f_ < 4; ++f_) \
    _Pragma("unroll") for (int j_ = 0; j_ < 2; ++j_) \
        accP[(F0) + f_][j_] = __builtin_amdgcn_mfma_f32_16x16x32_bf16( \
            af[f_ * 2 + kk_], fp[j_ * 2 + kk_], accP[(F0) + f_][j_], 0, 0, 0);

__global__ __launch_bounds__(512, 2) void gemm8_k(
    const u16* __restrict__ Bt, const u16* __restrict__ Wm, const u16* __restrict__ Wp,
    const float* __restrict__ bm, const float* __restrict__ bp,
    const float* __restrict__ asp,
    u16* __restrict__ item, float* __restrict__ scorep,
    int a0, int log2na, int nwg) {
    __shared__ u16 As[2][256 * 64];     // 64 KB
    __shared__ u16 Bms[2][128 * 64];    // 32 KB
    __shared__ u16 Bps[2][128 * 64];    // 32 KB

    int bid = blockIdx.x;
    int chunk = nwg >> 3;                       // XCD-aware swizzle (nwg % 8 == 0)
    int b = (bid & 7) * chunk + (bid >> 3);
    int nt = b & 3;                             // N-tile fastest: share A panel
    int al = (b >> 2) & ((1 << log2na) - 1);
    int mt = b >> (2 + log2na);
    int a  = a0 + al;

    int tid = threadIdx.x;
    int lane = tid & 63;
    int w  = tid >> 6;        // 0..7
    int wr = w >> 2;          // 0..1  (M half)
    int wc = w & 3;           // 0..3  (N quarter)
    int g = lane >> 4, r15 = lane & 15;

    const u16* Abase = Bt + (size_t)(mt * 256) * K2;
    const u16* Mbase = Wm + ((size_t)a * ND + nt * 128) * K2;
    const u16* Pbase = Wp + ((size_t)a * ND + nt * 128) * K2;

    // staging: linear LDS dest, inverse-swizzled global source
    auto stageA = [&](int buf, int ks, int r) {
        int row = r * 64 + (tid >> 3);
        int sl = tid & 7;
        int q = sl ^ (row & 7);
        gload16(Abase + (size_t)row * K2 + ks * 64 + q * 8, &As[buf][row * 64 + sl * 8]);
    };
    auto stageBm = [&](int buf, int ks, int r) {
        int row = r * 64 + (tid >> 3);
        int sl = tid & 7;
        int q = sl ^ (row & 7);
        gload16(Mbase + (size_t)row * K2 + ks * 64 + q * 8, &Bms[buf][row * 64 + sl * 8]);
    };
    auto stageBp = [&](int buf, int ks, int r) {
        int row = r * 64 + (tid >> 3);
        int sl = tid & 7;
        int q = sl ^ (row & 7);
        gload16(Pbase + (size_t)row * K2 + ks * 64 + q * 8, &Bps[buf][row * 64 + sl * 8]);
    };
    // swizzled fragment reads
    auto rdA = [&](int buf, int qd, int f, int kk) -> s16x8 {
        int row = wr * 128 + qd * 64 + f * 16 + r15;
        int slot = (kk * 4 + g) ^ (row & 7);
        return *(const s16x8*)&As[buf][row * 64 + slot * 8];
    };
    auto rdB = [&](int buf, int mat, int j, int kk) -> s16x8 {
        int row = wc * 32 + j * 16 + r15;
        int slot = (kk * 4 + g) ^ (row & 7);
        return mat ? *(const s16x8*)&Bps[buf][row * 64 + slot * 8]
                   : *(const s16x8*)&Bms[buf][row * 64 + slot * 8];
    };

    f32x4 accM[8][2], accP[8][2];
    #pragma unroll
    for (int i = 0; i < 8; ++i)
        #pragma unroll
        for (int j = 0; j < 2; ++j) { accM[i][j] = 0.0f; accP[i][j] = 0.0f; }

    s16x8 af[8], fm[4], fp[4];

    // ---- prologue: K0 fully + K1 minus A-odd (14 loads, read-order) ----
    stageA(0, 0, 0); stageA(0, 0, 2);
    stageBm(0, 0, 0); stageBm(0, 0, 1);
    stageBp(0, 0, 0); stageBp(0, 0, 1);
    stageA(0, 0, 1); stageA(0, 0, 3);
    stageA(1, 1, 0); stageA(1, 1, 2);
    stageBm(1, 1, 0); stageBm(1, 1, 1);
    stageBp(1, 1, 0); stageBp(1, 1, 1);
    WAITV(6); BAR();
    // invariant at each K-step start: 6 outstanding = {A02,Bm,Bp}(t+1)

    // ---- steady loop: K-steps 0..13 ----
    #pragma unroll 2
    for (int t = 0; t < 14; ++t) {
        const int cur = t & 1, nxt = cur ^ 1;
        // P1: reads A-even + Bm(cur); stage A-odd(t+1)
        RD_AQ(cur, 0) RD_FM(cur)
        stageA(nxt, t + 1, 1); stageA(nxt, t + 1, 3);
        BAR(); LGKM0();
        PRIO1 MMA_M(0) PRIO0
        BAR();
        // P2: reads Bp(cur); stage A-even(t+2)
        RD_FP(cur)
        stageA(cur, t + 2, 0); stageA(cur, t + 2, 2);
        BAR(); LGKM0();
        PRIO1 MMA_P(0) PRIO0
        BAR();
        // P3: reads A-odd(cur); stage Bm(t+2)
        RD_AQ(cur, 1)
        stageBm(cur, t + 2, 0); stageBm(cur, t + 2, 1);
        BAR(); LGKM0();
        PRIO1 MMA_M(4) PRIO0
        BAR();
        // P4: no reads; stage Bp(t+2); single per-K-step wait
        stageBp(cur, t + 2, 0); stageBp(cur, t + 2, 1);
        BAR();
        PRIO1 MMA_P(4) PRIO0
        WAITV(6); BAR();
    }

    // ---- K-step 14: only A-odd(15) stage remains; drain to 0 ----
    {
        const int cur = 0, nxt = 1;
        RD_AQ(cur, 0) RD_FM(cur)
        stageA(nxt, 15, 1); stageA(nxt, 15, 3);
        BAR(); LGKM0();
        PRIO1 MMA_M(0) PRIO0
        BAR();
        RD_FP(cur)
        BAR(); LGKM0();
        PRIO1 MMA_P(0) PRIO0
        BAR();
        RD_AQ(cur, 1)
        BAR(); LGKM0();
        PRIO1 MMA_M(4) PRIO0
        BAR();
        BAR();
        PRIO1 MMA_P(4) PRIO0
        WAITV(0); BAR();
    }
    // ---- K-step 15: reads only ----
    {
        const int cur = 1;
        RD_AQ(cur, 0) RD_FM(cur)
        BAR(); LGKM0();
        PRIO1 MMA_M(0) PRIO0
        BAR();
        RD_FP(cur)
        BAR(); LGKM0();
        PRIO1 MMA_P(0) PRIO0
        BAR();
        RD_AQ(cur, 1)
        BAR(); LGKM0();
        PRIO1 MMA_M(4) PRIO0
        BAR();
        PRIO1 MMA_P(4) PRIO0
    }

    // ---- epilogue: bias + sigmoid gate, item bf16 write, fused score partials ----
    int gc0 = nt * 128 + wc * 32 + r15;
    int gc1 = gc0 + 16;
    float bmv0 = bm[a * ND + gc0], bmv1 = bm[a * ND + gc1];
    float bpv0 = bp[a * ND + gc0], bpv1 = bp[a * ND + gc1];
    float aspw[4][2];
    #pragma unroll
    for (int jj = 0; jj < 4; ++jj) {
        int a2 = (g * 4 + jj) & 7;
        aspw[jj][0] = asp[a2 * ND + gc0];
        aspw[jj][1] = asp[a2 * ND + gc1];
    }
    #pragma unroll
    for (int i = 0; i < 8; ++i) {
        int rowb = mt * 256 + wr * 128 + i * 16 + g * 4;
        #pragma unroll
        for (int jj = 0; jj < 4; ++jj) {
            float m0 = accM[i][0][jj] + bmv0;
            float p0 = accP[i][0][jj] + bpv0;
            float v0 = p0 / (1.0f + __expf(-m0));
            float m1 = accM[i][1][jj] + bmv1;
            float p1 = accP[i][1][jj] + bpv1;
            float v1 = p1 / (1.0f + __expf(-m1));
            size_t rbase = ((size_t)al * MROWS + rowb + jj) * ND;
            item[rbase + gc0] = f2b(v0);
            item[rbase + gc1] = f2b(v1);
            float sv = v0 * aspw[jj][0] + v1 * aspw[jj][1];
            sv += __shfl_xor(sv, 1);
            sv += __shfl_xor(sv, 2);
            sv += __shfl_xor(sv, 4);
            sv += __shfl_xor(sv, 8);
            if (r15 == 0)
                scorep[((size_t)al * MROWS + rowb + jj) * 16 + nt * 4 + wc] = sv;
        }
    }
}

// ---------------- kernel 4: softmax(L) from score partials + weighted sum ----------------
__global__ __launch_bounds__(512) void attn_out_k(
    const u16* __restrict__ item, const float* __restrict__ scorep,
    float* __restrict__ out, int b0) {
    __shared__ float attn[512];
    __shared__ float red[4][512];
    int t = threadIdx.x;
    int bl = blockIdx.x >> 3;
    int ap = blockIdx.x & 7;
    int bg = b0 + bl;

    size_t R = (size_t)bl * 4096 + (size_t)t * 8 + ap;
    const f32x4* sp = (const f32x4*)(scorep + R * 16);
    f32x4 q0 = sp[0], q1 = sp[1], q2 = sp[2], q3 = sp[3];
    float s = (q0[0] + q0[1] + q0[2] + q0[3]) + (q1[0] + q1[1] + q1[2] + q1[3])
            + (q2[0] + q2[1] + q2[2] + q2[3]) + (q3[0] + q3[1] + q3[2] + q3[3]);

    red[0][t] = s;
    __syncthreads();
    for (int off = 256; off > 0; off >>= 1) {
        if (t < off) red[0][t] = fmaxf(red[0][t], red[0][t + off]);
        __syncthreads();
    }
    float mx = red[0][0];
    __syncthreads();
    float p = __expf(s - mx);
    red[0][t] = p;
    __syncthreads();
    for (int off = 256; off > 0; off >>= 1) {
        if (t < off) red[0][t] += red[0][t + off];
        __syncthreads();
    }
    float inv = 1.0f / red[0][0];
    attn[t] = p * inv;
    __syncthreads();

    // weighted sum: 4 l'-groups x 128 d-threads (4 d each), single item pass
    int gq = t >> 7, u = t & 127;
    float a0v = 0.f, a1v = 0.f, a2v = 0.f, a3v = 0.f;
    const u16* base2 = item + ((size_t)bl * 4096 + ap) * ND + 4 * u;
    for (int l = gq; l < 512; l += 4) {
        float wv = attn[l];
        u16x4 v = *(const u16x4*)(base2 + (size_t)l * 8 * ND);
        a0v += wv * b2f(v[0]); a1v += wv * b2f(v[1]);
        a2v += wv * b2f(v[2]); a3v += wv * b2f(v[3]);
    }
    red[gq][4 * u + 0] = a0v; red[gq][4 * u + 1] = a1v;
    red[gq][4 * u + 2] = a2v; red[gq][4 * u + 3] = a3v;
    __syncthreads();
    float o = red[0][t] + red[1][t] + red[2][t] + red[3][t];
    out[((size_t)bg * NA + ap) * ND + t] = o;
}

// ---------------- launcher ----------------
extern "C" void kernel_launch(void* const* d_in, const int* in_sizes, int n_in,
                              void* d_out, int out_size, void* d_ws, size_t ws_size,
                              hipStream_t stream) {
    const float* H   = (const float*)d_in[0];
    const float* U   = (const float*)d_in[1];
    const float* asp = (const float*)d_in[2];
    const float* Wmf = (const float*)d_in[3];
    const float* bmf = (const float*)d_in[4];
    const float* Wpf = (const float*)d_in[5];
    const float* bpf = (const float*)d_in[6];
    float* out = (float*)d_out;

    char* ws = (char*)d_ws;
    const size_t BATCH_BYTES = (size_t)MROWS * K2 * 2;        // 64 MB
    const size_t WT_BYTES    = (size_t)NA * ND * K2 * 2;      // 8 MB each
    u16* Bt = (u16*)(ws);
    u16* Wm = (u16*)(ws + BATCH_BYTES);
    u16* Wp = (u16*)(ws + BATCH_BYTES + WT_BYTES);
    size_t fixed = BATCH_BYTES + 2 * WT_BYTES;                 // 80 MB
    const size_t ITEM_PER_ASPECT  = (size_t)MROWS * ND * 2;    // 32 MB
    const size_t SCORE_PER_ASPECT = (size_t)MROWS * 16 * 4;    // 2 MB
    size_t avail = (ws_size > fixed) ? (ws_size - fixed) : 0;
    int na = (int)(avail / (ITEM_PER_ASPECT + SCORE_PER_ASPECT));
    if (na > NA) na = NA;
    if (na < 1) na = 1;
    int log2na = 0;
    while ((2 << log2na) <= na) ++log2na;
    na = 1 << log2na;
    u16*   item   = (u16*)(ws + fixed);
    float* scorep = (float*)(ws + fixed + (size_t)na * ITEM_PER_ASPECT);

    build_batch<<<4096, 256, 0, stream>>>(H, U, Bt);
    build_wt<<<4096, 256, 0, stream>>>(Wmf, Wpf, Wm, Wp);

    for (int a0 = 0; a0 < NA; a0 += na) {
        int n = (na < NA - a0) ? na : (NA - a0);
        gemm8_k<<<n * 512, 512, 0, stream>>>(Bt, Wm, Wp, bmf, bpf, asp,
                                             item, scorep, a0, log2na, n * 512);
        attn_out_k<<<n * 64, 512, 0, stream>>>(item, scorep, out, a0 * 8);
    }
}

// Round 5
// 699.594 us; speedup vs baseline: 1.0963x; 1.0009x over previous
//
#include <hip/hip_runtime.h>
#include <hip/hip_bf16.h>

// ---------------- types ----------------
typedef unsigned short u16;
typedef u16   u16x4 __attribute__((ext_vector_type(4)));
typedef u16   u16x8 __attribute__((ext_vector_type(8)));
typedef short s16x8 __attribute__((ext_vector_type(8)));
typedef float f32x4 __attribute__((ext_vector_type(4)));

// Problem constants
#define NB   64
#define NL   512
#define ND   512
#define NA   8
#define K2   1024        // 2*D
#define MROWS 32768      // B*L

__device__ __forceinline__ float b2f(u16 u) {
    unsigned int x = ((unsigned int)u) << 16;
    return __uint_as_float(x);
}
__device__ __forceinline__ u16 f2b(float f) {
    unsigned int x = __float_as_uint(f);
    unsigned int r = (x + 0x7fffu + ((x >> 16) & 1u)) >> 16;
    return (u16)r;
}

// permuted column position for original k within a 64-col K-block
__device__ __forceinline__ int permc(int k) {
    int ks  = k >> 6;
    int kr  = k & 63;
    int kk  = kr >> 5;
    int k32 = kr & 31;
    int h   = k32 >> 4;
    int rem = k32 & 15;
    int g   = rem >> 2;
    int e0  = rem & 3;
    return ks * 64 + kk * 32 + g * 8 + h * 4 + e0;
}

__device__ __forceinline__ void gload16(const u16* g, u16* l) {
    __builtin_amdgcn_global_load_lds(
        (const __attribute__((address_space(1))) unsigned int*)g,
        (__attribute__((address_space(3))) unsigned int*)l, 16, 0, 0);
}

// ---------------- kernel 1: build permuted bf16 Batch [32768][1024] ----------------
__global__ void build_batch(const float* __restrict__ H, const float* __restrict__ U,
                            u16* __restrict__ Bt) {
    size_t stride = (size_t)gridDim.x * blockDim.x;
    for (size_t idx = (size_t)blockIdx.x * blockDim.x + threadIdx.x;
         idx < (size_t)MROWS * 256; idx += stride) {
        int r  = (int)(idx >> 8);
        int c  = ((int)idx & 255) << 2;       // permuted col (multiple of 4)
        int ks = c >> 6;
        int w64 = c & 63;
        int cq = w64 >> 3;
        int h  = (w64 >> 2) & 1;
        int kbase = ks * 64 + (cq >> 2) * 32 + (cq & 3) * 4 + h * 16;
        const float* src;
        if (kbase < ND) src = H + (size_t)r * ND + kbase;
        else { int b = r >> 9; src = U + (size_t)b * ND + (kbase - ND); }
        f32x4 v = *(const f32x4*)src;
        u16x4 o;
        o[0] = f2b(v[0]); o[1] = f2b(v[1]); o[2] = f2b(v[2]); o[3] = f2b(v[3]);
        *(u16x4*)(Bt + (size_t)r * K2 + c) = o;
    }
}

// ---------------- kernel 2: W (A,1024,512) f32 -> Wt (A,512,1024) bf16 permuted ----------------
__global__ void build_wt(const float* __restrict__ Wmf, const float* __restrict__ Wpf,
                         u16* __restrict__ Wm, u16* __restrict__ Wp) {
    __shared__ float ld[32][65];
    int bid = blockIdx.x;
    int kt  = bid & 31;
    int dt  = (bid >> 5) & 7;
    int a   = (bid >> 8) & 7;
    int mat = bid >> 11;
    const float* W = mat ? Wpf : Wmf;
    u16* Wt = mat ? Wp : Wm;
    int k0 = kt * 32, d0 = dt * 64;
    int t = threadIdx.x;
    #pragma unroll
    for (int it = 0; it < 8; ++it) {
        int lin = it * 256 + t;
        int i = lin >> 6, j = lin & 63;
        ld[i][j] = W[((size_t)a * K2 + k0 + i) * ND + d0 + j];
    }
    __syncthreads();
    #pragma unroll
    for (int it = 0; it < 8; ++it) {
        int lin = it * 256 + t;
        int dl = lin >> 5, kl = lin & 31;
        int k = k0 + kl;
        Wt[((size_t)a * ND + d0 + dl) * K2 + permc(k)] = f2b(ld[kl][dl]);
    }
}

// ---------------- kernel 3: pipelined dual GEMM + gate + fused scores ----------------
// BM=256, BN=128, BK=64, 8 waves (2M x 4N), double-buffered LDS.
// Fence-free builtin barriers; compiler-counted lgkm waits; single
// inline-asm vmcnt(6) per K-step. MFMA order M-low, P-low, M-high, P-high
// so af[] can be reloaded (even->odd) without extra registers.
#define BAR()    do { __builtin_amdgcn_sched_barrier(0); \
                      __builtin_amdgcn_s_barrier(); \
                      __builtin_amdgcn_sched_barrier(0); } while (0)
#define WAITV(n) do { asm volatile("s_waitcnt vmcnt(" #n ")" ::: "memory"); \
                      __builtin_amdgcn_sched_barrier(0); } while (0)
#define PRIO1    __builtin_amdgcn_s_setprio(1);
#define PRIO0    __builtin_amdgcn_s_setprio(0);

#define RD_AQ(C,Q) \
    _Pragma("unroll") for (int f_ = 0; f_ < 4; ++f_) \
    _Pragma("unroll") for (int kk_ = 0; kk_ < 2; ++kk_) \
        af[f_ * 2 + kk_] = rdA((C), (Q), f_, kk_);

#define RD_FM(C) \
    _Pragma("unroll") for (int j_ = 0; j_ < 2; ++j_) \
    _Pragma("unroll") for (int kk_ = 0; kk_ < 2; ++kk_) \
        fm[j_ * 2 + kk_] = rdB((C), 0, j_, kk_);

#define RD_FP(C) \
    _Pragma("unroll") for (int j_ = 0; j_ < 2; ++j_) \
    _Pragma("unroll") for (int kk_ = 0; kk_ < 2; ++kk_) \
        fp[j_ * 2 + kk_] = rdB((C), 1, j_, kk_);

#define MMA_M(F0) \
    _Pragma("unroll") for (int kk_ = 0; kk_ < 2; ++kk_) \
    _Pragma("unroll") for (int f_ = 0; f_ < 4; ++f_) \
    _Pragma("unroll") for (int j_ = 0; j_ < 2; ++j_) \
        accM[(F0) + f_][j_] = __builtin_amdgcn_mfma_f32_16x16x32_bf16( \
            af[f_ * 2 + kk_], fm[j_ * 2 + kk_], accM[(F0) + f_][j_], 0, 0, 0);

#define MMA_P(F0) \
    _Pragma("unroll") for (int kk_ = 0; kk_ < 2; ++kk_) \
    _Pragma("unroll") for (int f_ = 0; f_ < 4; ++f_) \
    _Pragma("unroll") for (int j_ = 0; j_ < 2; ++j_) \
        accP[(F0) + f_][j_] = __builtin_amdgcn_mfma_f32_16x16x32_bf16( \
            af[f_ * 2 + kk_], fp[j_ * 2 + kk_], accP[(F0) + f_][j_], 0, 0, 0);

__global__ __launch_bounds__(512, 2) void gemm8_k(
    const u16* __restrict__ Bt, const u16* __restrict__ Wm, const u16* __restrict__ Wp,
    const float* __restrict__ bm, const float* __restrict__ bp,
    const float* __restrict__ asp,
    u16* __restrict__ item, float* __restrict__ scorep,
    int a0, int log2na, int nwg) {
    __shared__ u16 As[2][256 * 64];     // 64 KB
    __shared__ u16 Bms[2][128 * 64];    // 32 KB
    __shared__ u16 Bps[2][128 * 64];    // 32 KB

    int bid = blockIdx.x;
    int chunk = nwg >> 3;                       // XCD-aware swizzle (nwg % 8 == 0)
    int b = (bid & 7) * chunk + (bid >> 3);
    int nt = b & 3;                             // N-tile fastest: share A panel
    int al = (b >> 2) & ((1 << log2na) - 1);
    int mt = b >> (2 + log2na);
    int a  = a0 + al;

    int tid = threadIdx.x;
    int lane = tid & 63;
    int w  = tid >> 6;        // 0..7
    int wr = w >> 2;          // 0..1  (M half)
    int wc = w & 3;           // 0..3  (N quarter)
    int g = lane >> 4, r15 = lane & 15;

    const u16* Abase = Bt + (size_t)(mt * 256) * K2;
    const u16* Mbase = Wm + ((size_t)a * ND + nt * 128) * K2;
    const u16* Pbase = Wp + ((size_t)a * ND + nt * 128) * K2;

    // staging: linear LDS dest, inverse-swizzled global source
    auto stageA = [&](int buf, int ks, int r) {
        int row = r * 64 + (tid >> 3);
        int sl = tid & 7;
        int q = sl ^ (row & 7);
        gload16(Abase + (size_t)row * K2 + ks * 64 + q * 8, &As[buf][row * 64 + sl * 8]);
    };
    auto stageBm = [&](int buf, int ks, int r) {
        int row = r * 64 + (tid >> 3);
        int sl = tid & 7;
        int q = sl ^ (row & 7);
        gload16(Mbase + (size_t)row * K2 + ks * 64 + q * 8, &Bms[buf][row * 64 + sl * 8]);
    };
    auto stageBp = [&](int buf, int ks, int r) {
        int row = r * 64 + (tid >> 3);
        int sl = tid & 7;
        int q = sl ^ (row & 7);
        gload16(Pbase + (size_t)row * K2 + ks * 64 + q * 8, &Bps[buf][row * 64 + sl * 8]);
    };
    // swizzled fragment reads
    auto rdA = [&](int buf, int qd, int f, int kk) -> s16x8 {
        int row = wr * 128 + qd * 64 + f * 16 + r15;
        int slot = (kk * 4 + g) ^ (row & 7);
        return *(const s16x8*)&As[buf][row * 64 + slot * 8];
    };
    auto rdB = [&](int buf, int mat, int j, int kk) -> s16x8 {
        int row = wc * 32 + j * 16 + r15;
        int slot = (kk * 4 + g) ^ (row & 7);
        return mat ? *(const s16x8*)&Bps[buf][row * 64 + slot * 8]
                   : *(const s16x8*)&Bms[buf][row * 64 + slot * 8];
    };

    f32x4 accM[8][2], accP[8][2];
    #pragma unroll
    for (int i = 0; i < 8; ++i)
        #pragma unroll
        for (int j = 0; j < 2; ++j) { accM[i][j] = 0.0f; accP[i][j] = 0.0f; }

    s16x8 af[8], fm[4], fp[4];

    // ---- prologue: K0 fully + K1 minus A-odd (14 loads, read-order) ----
    stageA(0, 0, 0); stageA(0, 0, 2);
    stageBm(0, 0, 0); stageBm(0, 0, 1);
    stageBp(0, 0, 0); stageBp(0, 0, 1);
    stageA(0, 0, 1); stageA(0, 0, 3);
    stageA(1, 1, 0); stageA(1, 1, 2);
    stageBm(1, 1, 0); stageBm(1, 1, 1);
    stageBp(1, 1, 0); stageBp(1, 1, 1);
    WAITV(6); BAR();
    // invariant at each K-step start: 6 outstanding = {A-even,Bm,Bp}(t+1),
    // and ALL of buffer(t) is vmcnt-complete.

    // ---- steady loop: K-steps 0..13 ----
    #pragma unroll 2
    for (int t = 0; t < 14; ++t) {
        const int cur = t & 1, nxt = cur ^ 1;
        // P1: read af-even + fm (consumed here) + fp (ahead); stage A-odd(t+1)
        RD_AQ(cur, 0) RD_FM(cur) RD_FP(cur)
        stageA(nxt, t + 1, 1); stageA(nxt, t + 1, 3);
        BAR();
        PRIO1 MMA_M(0) PRIO0          // counted lgkm leaves fp in flight
        BAR();
        // P2: no reads; stage A-even(t+2); fp already drained under M-low
        stageA(cur, t + 2, 0); stageA(cur, t + 2, 2);
        BAR();
        PRIO1 MMA_P(0) PRIO0          // af still holds EVEN fragments
        BAR();
        // P3: reload af <- A-odd; stage Bm(t+2)
        RD_AQ(cur, 1)
        stageBm(cur, t + 2, 0); stageBm(cur, t + 2, 1);
        BAR();
        PRIO1 MMA_M(4) PRIO0
        BAR();
        // P4: no reads; stage Bp(t+2); single per-K-step vmcnt wait
        stageBp(cur, t + 2, 0); stageBp(cur, t + 2, 1);
        BAR();
        PRIO1 MMA_P(4) PRIO0
        WAITV(6); BAR();
    }

    // ---- K-step 14: only A-odd(15) stage remains; drain to 0 ----
    {
        const int cur = 0, nxt = 1;
        RD_AQ(cur, 0) RD_FM(cur) RD_FP(cur)
        stageA(nxt, 15, 1); stageA(nxt, 15, 3);
        BAR();
        PRIO1 MMA_M(0) PRIO0
        BAR();
        PRIO1 MMA_P(0) PRIO0
        RD_AQ(cur, 1)
        PRIO1 MMA_M(4) PRIO0
        PRIO1 MMA_P(4) PRIO0
        WAITV(0); BAR();
    }
    // ---- K-step 15: reads only ----
    {
        const int cur = 1;
        RD_AQ(cur, 0) RD_FM(cur) RD_FP(cur)
        PRIO1 MMA_M(0) PRIO0
        PRIO1 MMA_P(0) PRIO0
        RD_AQ(cur, 1)
        PRIO1 MMA_M(4) PRIO0
        PRIO1 MMA_P(4) PRIO0
    }

    // ---- epilogue: bias + sigmoid gate, item bf16 write, fused score partials ----
    int gc0 = nt * 128 + wc * 32 + r15;
    int gc1 = gc0 + 16;
    float bmv0 = bm[a * ND + gc0], bmv1 = bm[a * ND + gc1];
    float bpv0 = bp[a * ND + gc0], bpv1 = bp[a * ND + gc1];
    float aspw[4][2];
    #pragma unroll
    for (int jj = 0; jj < 4; ++jj) {
        int a2 = (g * 4 + jj) & 7;
        aspw[jj][0] = asp[a2 * ND + gc0];
        aspw[jj][1] = asp[a2 * ND + gc1];
    }
    #pragma unroll
    for (int i = 0; i < 8; ++i) {
        int rowb = mt * 256 + wr * 128 + i * 16 + g * 4;
        #pragma unroll
        for (int jj = 0; jj < 4; ++jj) {
            float m0 = accM[i][0][jj] + bmv0;
            float p0 = accP[i][0][jj] + bpv0;
            float v0 = p0 / (1.0f + __expf(-m0));
            float m1 = accM[i][1][jj] + bmv1;
            float p1 = accP[i][1][jj] + bpv1;
            float v1 = p1 / (1.0f + __expf(-m1));
            size_t rbase = ((size_t)al * MROWS + rowb + jj) * ND;
            item[rbase + gc0] = f2b(v0);
            item[rbase + gc1] = f2b(v1);
            float sv = v0 * aspw[jj][0] + v1 * aspw[jj][1];
            sv += __shfl_xor(sv, 1);
            sv += __shfl_xor(sv, 2);
            sv += __shfl_xor(sv, 4);
            sv += __shfl_xor(sv, 8);
            if (r15 == 0)
                scorep[((size_t)al * MROWS + rowb + jj) * 16 + nt * 4 + wc] = sv;
        }
    }
}

// ---------------- kernel 4: softmax(L) from score partials + weighted sum ----------------
__global__ __launch_bounds__(512) void attn_out_k(
    const u16* __restrict__ item, const float* __restrict__ scorep,
    float* __restrict__ out, int b0) {
    __shared__ float attn[512];
    __shared__ float red[4][512];
    int t = threadIdx.x;
    int bl = blockIdx.x >> 3;
    int ap = blockIdx.x & 7;
    int bg = b0 + bl;

    size_t R = (size_t)bl * 4096 + (size_t)t * 8 + ap;
    const f32x4* sp = (const f32x4*)(scorep + R * 16);
    f32x4 q0 = sp[0], q1 = sp[1], q2 = sp[2], q3 = sp[3];
    float s = (q0[0] + q0[1] + q0[2] + q0[3]) + (q1[0] + q1[1] + q1[2] + q1[3])
            + (q2[0] + q2[1] + q2[2] + q2[3]) + (q3[0] + q3[1] + q3[2] + q3[3]);

    red[0][t] = s;
    __syncthreads();
    for (int off = 256; off > 0; off >>= 1) {
        if (t < off) red[0][t] = fmaxf(red[0][t], red[0][t + off]);
        __syncthreads();
    }
    float mx = red[0][0];
    __syncthreads();
    float p = __expf(s - mx);
    red[0][t] = p;
    __syncthreads();
    for (int off = 256; off > 0; off >>= 1) {
        if (t < off) red[0][t] += red[0][t + off];
        __syncthreads();
    }
    float inv = 1.0f / red[0][0];
    attn[t] = p * inv;
    __syncthreads();

    // weighted sum: 4 l'-groups x 128 d-threads (4 d each), single item pass
    int gq = t >> 7, u = t & 127;
    float a0v = 0.f, a1v = 0.f, a2v = 0.f, a3v = 0.f;
    const u16* base2 = item + ((size_t)bl * 4096 + ap) * ND + 4 * u;
    for (int l = gq; l < 512; l += 4) {
        float wv = attn[l];
        u16x4 v = *(const u16x4*)(base2 + (size_t)l * 8 * ND);
        a0v += wv * b2f(v[0]); a1v += wv * b2f(v[1]);
        a2v += wv * b2f(v[2]); a3v += wv * b2f(v[3]);
    }
    red[gq][4 * u + 0] = a0v; red[gq][4 * u + 1] = a1v;
    red[gq][4 * u + 2] = a2v; red[gq][4 * u + 3] = a3v;
    __syncthreads();
    float o = red[0][t] + red[1][t] + red[2][t] + red[3][t];
    out[((size_t)bg * NA + ap) * ND + t] = o;
}

// ---------------- launcher ----------------
extern "C" void kernel_launch(void* const* d_in, const int* in_sizes, int n_in,
                              void* d_out, int out_size, void* d_ws, size_t ws_size,
                              hipStream_t stream) {
    const float* H   = (const float*)d_in[0];
    const float* U   = (const float*)d_in[1];
    const float* asp = (const float*)d_in[2];
    const float* Wmf = (const float*)d_in[3];
    const float* bmf = (const float*)d_in[4];
    const float* Wpf = (const float*)d_in[5];
    const float* bpf = (const float*)d_in[6];
    float* out = (float*)d_out;

    char* ws = (char*)d_ws;
    const size_t BATCH_BYTES = (size_t)MROWS * K2 * 2;        // 64 MB
    const size_t WT_BYTES    = (size_t)NA * ND * K2 * 2;      // 8 MB each
    u16* Bt = (u16*)(ws);
    u16* Wm = (u16*)(ws + BATCH_BYTES);
    u16* Wp = (u16*)(ws + BATCH_BYTES + WT_BYTES);
    size_t fixed = BATCH_BYTES + 2 * WT_BYTES;                 // 80 MB
    const size_t ITEM_PER_ASPECT  = (size_t)MROWS * ND * 2;    // 32 MB
    const size_t SCORE_PER_ASPECT = (size_t)MROWS * 16 * 4;    // 2 MB
    size_t avail = (ws_size > fixed) ? (ws_size - fixed) : 0;
    int na = (int)(avail / (ITEM_PER_ASPECT + SCORE_PER_ASPECT));
    if (na > NA) na = NA;
    if (na < 1) na = 1;
    int log2na = 0;
    while ((2 << log2na) <= na) ++log2na;
    na = 1 << log2na;
    u16*   item   = (u16*)(ws + fixed);
    float* scorep = (float*)(ws + fixed + (size_t)na * ITEM_PER_ASPECT);

    build_batch<<<4096, 256, 0, stream>>>(H, U, Bt);
    build_wt<<<4096, 256, 0, stream>>>(Wmf, Wpf, Wm, Wp);

    for (int a0 = 0; a0 < NA; a0 += na) {
        int n = (na < NA - a0) ? na : (NA - a0);
        gemm8_k<<<n * 512, 512, 0, stream>>>(Bt, Wm, Wp, bmf, bpf, asp,
                                             item, scorep, a0, log2na, n * 512);
        attn_out_k<<<n * 64, 512, 0, stream>>>(item, scorep, out, a0 * 8);
    }
}